// Round 2
// baseline (448.045 us; speedup 1.0000x reference)
//
#include <hip/hip_runtime.h>
#include <stdint.h>
#include <stddef.h>

typedef __attribute__((ext_vector_type(4))) float f32x4;
typedef __attribute__((ext_vector_type(2))) float f32x2;
typedef __attribute__((ext_vector_type(8))) __bf16 bf16x8;

#define DEVI static __device__ __forceinline__

DEVI f32x4 mfma16(bf16x8 a, bf16x8 b, f32x4 c){
  return __builtin_amdgcn_mfma_f32_16x16x32_bf16(a, b, c, 0, 0, 0);
}

DEVI bf16x8 cvt8(f32x4 a, f32x4 b){
  bf16x8 o;
  o[0]=(__bf16)a[0]; o[1]=(__bf16)a[1]; o[2]=(__bf16)a[2]; o[3]=(__bf16)a[3];
  o[4]=(__bf16)b[0]; o[5]=(__bf16)b[1]; o[6]=(__bf16)b[2]; o[7]=(__bf16)b[3];
  return o;
}

DEVI float fast_tanh(float x){ return 1.f - 2.f/(__expf(2.f*x)+1.f); }
DEVI float sigm(float x){ return 1.f/(1.f+__expf(-x)); }

// ---------------------------------------------------------------------------
// xe_w f32 [512 a][512 x] -> bf16, tiled (nt,kt) 64x64, slot-linear with
// chunk-XOR swizzle so GEMM ds_read_b128 is bank-conflict-free.
// slot s in tile: r=s>>3, cp=s&7, holds global k-chunk cg = cp ^ (r&7).
__global__ __launch_bounds__(256) void cvt_xew(const float* __restrict__ xe_w,
                                               __bf16* __restrict__ wswz){
  int g = blockIdx.x*256 + threadIdx.x;   // 0..32767
  int tile = g >> 9;                      // nt*8 + kt
  int s = g & 511;
  int nt = tile >> 3, kt = tile & 7;
  int r = s >> 3, cp = s & 7;
  int cg = cp ^ (r & 7);
  const float* src = xe_w + (size_t)(nt*64 + r)*512 + kt*64 + cg*8;
  f32x4 a = *(const f32x4*)src;
  f32x4 b = *(const f32x4*)(src + 4);
  *(bf16x8*)(wswz + (size_t)g*8) = cvt8(a, b);
}

// ---------------------------------------------------------------------------
// Generic C[M,N] = A[M,K] * W[N,K]^T + bias0 + bias1 (f32 out, tail-guarded).
// 64x64 tile, 4 waves (each 32x32 = 2x2 frags of 16x16x32 bf16 MFMA), BK=64,
// f32->bf16 conversion during LDS staging, chunk-XOR swizzle.
__global__ __launch_bounds__(256) void gemm_bt(
    const float* __restrict__ A, const float* __restrict__ W,
    const float* __restrict__ bias0, const float* __restrict__ bias1,
    float* __restrict__ Cf, int K, int Nreal, int ldc)
{
  const int tid  = threadIdx.x;
  const int lane = tid & 63;
  const int wid  = tid >> 6;
  const int wr = wid >> 1, wc = wid & 1;
  const int n0 = blockIdx.x * 64;
  const int m0 = blockIdx.y * 64;

  __shared__ __bf16 As[64*64];
  __shared__ __bf16 Wt[64*64];

  f32x4 acc[2][2] = {};

  const int nkt = K >> 6;
  for (int kt = 0; kt < nkt; ++kt){
    #pragma unroll
    for (int ss = 0; ss < 2; ++ss){
      int s  = ss*256 + tid;
      int r  = s >> 3;
      int cp = s & 7;
      int cg = cp ^ (r & 7);
      {
        const float* g = A + (size_t)(m0 + r)*K + kt*64 + cg*8;
        f32x4 v0 = *(const f32x4*)g;
        f32x4 v1 = *(const f32x4*)(g + 4);
        *(bf16x8*)(As + (size_t)s*8) = cvt8(v0, v1);
      }
      {
        int rw = n0 + r;
        if (rw >= Nreal) rw = Nreal - 1;   // clamp for N=6625 tail (results discarded)
        const float* g = W + (size_t)rw*K + kt*64 + cg*8;
        f32x4 v0 = *(const f32x4*)g;
        f32x4 v1 = *(const f32x4*)(g + 4);
        *(bf16x8*)(Wt + (size_t)s*8) = cvt8(v0, v1);
      }
    }
    __syncthreads();
    #pragma unroll
    for (int kk = 0; kk < 2; ++kk){
      bf16x8 af[2], wf[2];
      #pragma unroll
      for (int mi = 0; mi < 2; ++mi){
        int r  = wr*32 + mi*16 + (lane & 15);
        int c  = kk*4 + (lane >> 4);
        int cs = c ^ (r & 7);
        af[mi] = *(const bf16x8*)(As + (size_t)r*64 + cs*8);
      }
      #pragma unroll
      for (int ni = 0; ni < 2; ++ni){
        int r  = wc*32 + ni*16 + (lane & 15);
        int c  = kk*4 + (lane >> 4);
        int cs = c ^ (r & 7);
        wf[ni] = *(const bf16x8*)(Wt + (size_t)r*64 + cs*8);
      }
      #pragma unroll
      for (int mi = 0; mi < 2; ++mi)
        #pragma unroll
        for (int ni = 0; ni < 2; ++ni)
          acc[mi][ni] = mfma16(af[mi], wf[ni], acc[mi][ni]);
    }
    __syncthreads();
  }

  #pragma unroll
  for (int mi = 0; mi < 2; ++mi){
    #pragma unroll
    for (int ni = 0; ni < 2; ++ni){
      int rbase = m0 + wr*32 + mi*16 + (lane >> 4)*4;
      int col   = n0 + wc*32 + ni*16 + (lane & 15);
      if (col < Nreal){
        float bb = 0.f;
        if (bias0) bb += bias0[col];
        if (bias1) bb += bias1[col];
        #pragma unroll
        for (int r4 = 0; r4 < 4; ++r4){
          Cf[(size_t)(rbase + r4)*ldc + col] = acc[mi][ni][r4] + bb;
        }
      }
    }
  }
}

// ---------------------------------------------------------------------------
// Attention scores: per block, 64 rows (one b), x-tile [64][512] bf16 in LDS
// (staged once, f32->bf16, chunk-XOR swizzle), loop 8 n-tiles x 8 k-tiles.
// Epilogue: tanh(xProj + sProjPlus)*we_w, reduce over n -> scores[B*T].
__global__ __launch_bounds__(256) void attn_scores(
    const float* __restrict__ x, const __bf16* __restrict__ wswz,
    const float* __restrict__ sProjPlus, const float* __restrict__ we_w,
    float* __restrict__ scores)
{
  const int tid  = threadIdx.x;
  const int lane = tid & 63;
  const int wid  = tid >> 6;
  const int wr = wid >> 1, wc = wid & 1;
  const int m0 = blockIdx.x * 64;     // global row = b*256 + t
  const int b  = m0 >> 8;

  __shared__ __bf16 Xs[64*512];       // 64 KB
  __shared__ __bf16 Ws[64*64];        // 8 KB
  __shared__ float  sc[2][64];

  if (tid < 64){ sc[0][tid] = 0.f; sc[1][tid] = 0.f; }

  // stage x tile: 4096 slots of 8 bf16; slot s: r=s>>6, cp=s&63, cg=cp^(r&7)
  #pragma unroll 4
  for (int i = 0; i < 16; ++i){
    int s  = i*256 + tid;
    int r  = s >> 6;
    int cp = s & 63;
    int cg = cp ^ (r & 7);
    const float* g = x + (size_t)(m0 + r)*512 + cg*8;
    f32x4 v0 = *(const f32x4*)g;
    f32x4 v1 = *(const f32x4*)(g + 4);
    *(bf16x8*)(Xs + (size_t)s*8) = cvt8(v0, v1);
  }
  __syncthreads();

  #pragma unroll 1
  for (int nt = 0; nt < 8; ++nt){
    f32x4 acc[2][2] = {};
    #pragma unroll 1
    for (int kt = 0; kt < 8; ++kt){
      // stage pre-swizzled, pre-converted xe_w tile (straight copy)
      const bf16x8* wsrc = (const bf16x8*)(wswz + (size_t)(nt*8 + kt)*4096);
      bf16x8 w0 = wsrc[tid];
      bf16x8 w1 = wsrc[tid + 256];
      ((bf16x8*)Ws)[tid]       = w0;
      ((bf16x8*)Ws)[tid + 256] = w1;
      __syncthreads();
      #pragma unroll
      for (int kk = 0; kk < 2; ++kk){
        bf16x8 af[2], wf[2];
        #pragma unroll
        for (int mi = 0; mi < 2; ++mi){
          int r  = wr*32 + mi*16 + (lane & 15);
          int c  = kt*8 + kk*4 + (lane >> 4);
          int cs = c ^ (r & 7);
          af[mi] = *(const bf16x8*)(Xs + (size_t)r*512 + cs*8);
        }
        #pragma unroll
        for (int ni = 0; ni < 2; ++ni){
          int r  = wc*32 + ni*16 + (lane & 15);
          int c  = kk*4 + (lane >> 4);
          int cs = c ^ (r & 7);
          wf[ni] = *(const bf16x8*)(Ws + (size_t)r*64 + cs*8);
        }
        #pragma unroll
        for (int mi = 0; mi < 2; ++mi)
          #pragma unroll
          for (int ni = 0; ni < 2; ++ni)
            acc[mi][ni] = mfma16(af[mi], wf[ni], acc[mi][ni]);
      }
      __syncthreads();
    }
    // epilogue for this n-tile: tanh + weighted reduce over columns
    float part[2][4] = {};
    #pragma unroll
    for (int ni = 0; ni < 2; ++ni){
      int col  = nt*64 + wc*32 + ni*16 + (lane & 15);
      float sp = sProjPlus[b*512 + col];
      float wv = we_w[col];
      #pragma unroll
      for (int mi = 0; mi < 2; ++mi)
        #pragma unroll
        for (int r4 = 0; r4 < 4; ++r4){
          float t = fast_tanh(acc[mi][ni][r4] + sp);
          part[mi][r4] += t * wv;
        }
    }
    #pragma unroll
    for (int mi = 0; mi < 2; ++mi)
      #pragma unroll
      for (int r4 = 0; r4 < 4; ++r4){
        float v = part[mi][r4];
        v += __shfl_xor(v, 1);
        v += __shfl_xor(v, 2);
        v += __shfl_xor(v, 4);
        v += __shfl_xor(v, 8);
        if ((lane & 15) == 0){
          int row = wr*32 + mi*16 + (lane >> 4)*4 + r4;
          sc[wc][row] += v;
        }
      }
  }
  __syncthreads();
  if (tid < 64) scores[m0 + tid] = sc[0][tid] + sc[1][tid];
}

// ---------------------------------------------------------------------------
__global__ __launch_bounds__(256) void softmax_k(const float* __restrict__ scores,
                                                 float* __restrict__ alpha){
  int b = blockIdx.x, t = threadIdx.x;
  __shared__ float red[256];
  float v = scores[b*256 + t];
  red[t] = v; __syncthreads();
  for (int o = 128; o > 0; o >>= 1){
    if (t < o) red[t] = fmaxf(red[t], red[t+o]);
    __syncthreads();
  }
  float m = red[0]; __syncthreads();
  float e = __expf(v - m);
  red[t] = e; __syncthreads();
  for (int o = 128; o > 0; o >>= 1){
    if (t < o) red[t] += red[t+o];
    __syncthreads();
  }
  alpha[b*256 + t] = e / red[0];
}

// ---------------------------------------------------------------------------
// context[b,:] = sum_t alpha[b,t] * x[b,t,:]; cc = [yProj | context] (f32)
__global__ __launch_bounds__(256) void context_cc(
    const float* __restrict__ x, const float* __restrict__ alpha,
    const float* __restrict__ emb, const int* __restrict__ yPrev,
    float* __restrict__ cc)
{
  int b = blockIdx.x, t = threadIdx.x;
  __shared__ float al[256];
  al[t] = alpha[b*256 + t];
  __syncthreads();
  f32x2 acc = {0.f, 0.f};
  const f32x2* xb = (const f32x2*)(x + (size_t)b*256*512) + t;  // cols 2t,2t+1
  #pragma unroll 4
  for (int i = 0; i < 256; ++i){
    f32x2 v = xb[(size_t)i*256];
    acc.x += al[i]*v.x;
    acc.y += al[i]*v.y;
  }
  int yp = yPrev[b];
  f32x2 e2 = ((const f32x2*)(emb + (size_t)yp*512))[t];
  f32x2* ccb = (f32x2*)(cc + (size_t)b*1024);
  ccb[t]       = e2;    // yProj -> cols [0,512)
  ccb[256 + t] = acc;   // context -> cols [512,1024)
}

// ---------------------------------------------------------------------------
__global__ __launch_bounds__(256) void gates_k(
    const float* __restrict__ gi, const float* __restrict__ gh,
    const float* __restrict__ s, float* __restrict__ h_out)
{
  int idx = blockIdx.x*256 + threadIdx.x;   // 0..131071
  int b = idx >> 9, j = idx & 511;
  const float* gib = gi + (size_t)b*1536;
  const float* ghb = gh + (size_t)b*1536;
  float r  = sigm(gib[j]        + ghb[j]);
  float z  = sigm(gib[512 + j]  + ghb[512 + j]);
  float nv = fast_tanh(gib[1024 + j] + r*ghb[1024 + j]);
  float sv = s[idx];
  float h  = (1.f - z)*nv + z*sv;
  h_out[idx] = h;
}

// ---------------------------------------------------------------------------
extern "C" void kernel_launch(void* const* d_in, const int* in_sizes, int n_in,
                              void* d_out, int out_size, void* d_ws, size_t ws_size,
                              hipStream_t stream)
{
  const float* x     = (const float*)d_in[0];
  const float* sPrev = (const float*)d_in[1];   // (1,B,SD) -> [256,512]
  const int*   yPrev = (const int*)d_in[2];
  const float* xe_w  = (const float*)d_in[3];
  const float* xe_b  = (const float*)d_in[4];
  const float* se_w  = (const float*)d_in[5];
  const float* se_b  = (const float*)d_in[6];
  const float* we_w  = (const float*)d_in[7];
  // d_in[8] = we_b: constant shift, cancels in softmax -> unused
  const float* emb   = (const float*)d_in[9];
  const float* w_ih  = (const float*)d_in[10];
  const float* w_hh  = (const float*)d_in[11];
  const float* b_ih  = (const float*)d_in[12];
  const float* b_hh  = (const float*)d_in[13];
  const float* fc_w  = (const float*)d_in[14];
  const float* fc_b  = (const float*)d_in[15];

  char* ws = (char*)d_ws;
  __bf16* wswz  = (__bf16*)(ws);                // 524288 B (xe_w bf16 swizzled)
  float* sProjP = (float*)(ws + 524288);        // 524288 B  [256,512]
  float* gh     = (float*)(ws + 1048576);       // 1572864 B [256,1536]
  float* scores = (float*)(ws + 2621440);       // 262144 B  [256,256]
  float* alpha  = (float*)(ws + 2883584);       // 262144 B
  float* cc     = (float*)(ws + 3145728);       // 1048576 B [256,1024]
  float* gi     = (float*)(ws + 4194304);       // 1572864 B [256,1536]
  // total ws use: 5767168 B

  // f32 outputs, concatenated in reference return order: logits [256,6625], h [256,512]
  float* logits_out = (float*)d_out;
  float* h_out      = logits_out + (size_t)256*6625;

  cvt_xew<<<128, 256, 0, stream>>>(xe_w, wswz);
  // sProjPlus = s @ se_w^T + se_b + xe_b
  gemm_bt<<<dim3(8,4),  256, 0, stream>>>(sPrev, se_w, se_b, xe_b, sProjP, 512, 512, 512);
  // gh = s @ w_hh^T + b_hh
  gemm_bt<<<dim3(24,4), 256, 0, stream>>>(sPrev, w_hh, b_hh, nullptr, gh, 512, 1536, 1536);
  attn_scores<<<1024, 256, 0, stream>>>(x, wswz, sProjP, we_w, scores);
  softmax_k<<<256, 256, 0, stream>>>(scores, alpha);
  context_cc<<<256, 256, 0, stream>>>(x, alpha, emb, yPrev, cc);
  // gi = cc @ w_ih^T + b_ih
  gemm_bt<<<dim3(24,4), 256, 0, stream>>>(cc, w_ih, b_ih, nullptr, gi, 1024, 1536, 1536);
  gates_k<<<512, 256, 0, stream>>>(gi, gh, sPrev, h_out);
  // logits = h @ fc_w^T + fc_b (reads h from d_out; N=6625 tail-guarded)
  gemm_bt<<<dim3(104,4), 256, 0, stream>>>(h_out, fc_w, fc_b, nullptr, logits_out, 512, 6625, 6625);
}

// Round 3
// 392.566 us; speedup vs baseline: 1.1413x; 1.1413x over previous
//
#include <hip/hip_runtime.h>
#include <stdint.h>
#include <stddef.h>

typedef __attribute__((ext_vector_type(4))) float f32x4;
typedef __attribute__((ext_vector_type(2))) float f32x2;
typedef __attribute__((ext_vector_type(8))) __bf16 bf16x8;

#define DEVI static __device__ __forceinline__

DEVI f32x4 mfma16(bf16x8 a, bf16x8 b, f32x4 c){
  return __builtin_amdgcn_mfma_f32_16x16x32_bf16(a, b, c, 0, 0, 0);
}

DEVI bf16x8 cvt8(f32x4 a, f32x4 b){
  bf16x8 o;
  o[0]=(__bf16)a[0]; o[1]=(__bf16)a[1]; o[2]=(__bf16)a[2]; o[3]=(__bf16)a[3];
  o[4]=(__bf16)b[0]; o[5]=(__bf16)b[1]; o[6]=(__bf16)b[2]; o[7]=(__bf16)b[3];
  return o;
}

DEVI float fast_tanh(float x){ return 1.f - 2.f/(__expf(2.f*x)+1.f); }
DEVI float sigm(float x){ return 1.f/(1.f+__expf(-x)); }

// ---------------------------------------------------------------------------
// xe_w f32 [512 a][512 x] -> bf16, tiled (nt,kt) 64x64, slot-linear with
// chunk-XOR swizzle. slot s in tile: r=s>>3, cp=s&7, holds k-chunk cg=cp^(r&7).
__global__ __launch_bounds__(256) void cvt_xew(const float* __restrict__ xe_w,
                                               __bf16* __restrict__ wswz){
  int g = blockIdx.x*256 + threadIdx.x;   // 0..32767
  int tile = g >> 9;                      // nt*8 + kt
  int s = g & 511;
  int nt = tile >> 3, kt = tile & 7;
  int r = s >> 3, cp = s & 7;
  int cg = cp ^ (r & 7);
  const float* src = xe_w + (size_t)(nt*64 + r)*512 + kt*64 + cg*8;
  f32x4 a = *(const f32x4*)src;
  f32x4 b = *(const f32x4*)(src + 4);
  *(bf16x8*)(wswz + (size_t)g*8) = cvt8(a, b);
}

// ---------------------------------------------------------------------------
// 64x64-tile GEMM core (C = A*W^T + b0 + b1), bf16 MFMA, XOR-swizzled LDS.
DEVI void gemm64_core(const float* __restrict__ A, const float* __restrict__ W,
                      const float* __restrict__ bias0, const float* __restrict__ bias1,
                      float* __restrict__ Cf, int K, int Nreal, int ldc,
                      int m0, int n0, __bf16* As, __bf16* Wt)
{
  const int tid  = threadIdx.x;
  const int lane = tid & 63;
  const int wid  = tid >> 6;
  const int wr = wid >> 1, wc = wid & 1;

  f32x4 acc[2][2] = {};
  const int nkt = K >> 6;
  for (int kt = 0; kt < nkt; ++kt){
    #pragma unroll
    for (int ss = 0; ss < 2; ++ss){
      int s  = ss*256 + tid;
      int r  = s >> 3;
      int cp = s & 7;
      int cg = cp ^ (r & 7);
      {
        const float* g = A + (size_t)(m0 + r)*K + kt*64 + cg*8;
        f32x4 v0 = *(const f32x4*)g;
        f32x4 v1 = *(const f32x4*)(g + 4);
        *(bf16x8*)(As + (size_t)s*8) = cvt8(v0, v1);
      }
      {
        int rw = n0 + r;
        if (rw >= Nreal) rw = Nreal - 1;
        const float* g = W + (size_t)rw*K + kt*64 + cg*8;
        f32x4 v0 = *(const f32x4*)g;
        f32x4 v1 = *(const f32x4*)(g + 4);
        *(bf16x8*)(Wt + (size_t)s*8) = cvt8(v0, v1);
      }
    }
    __syncthreads();
    #pragma unroll
    for (int kk = 0; kk < 2; ++kk){
      bf16x8 af[2], wf[2];
      #pragma unroll
      for (int mi = 0; mi < 2; ++mi){
        int r  = wr*32 + mi*16 + (lane & 15);
        int c  = kk*4 + (lane >> 4);
        int cs = c ^ (r & 7);
        af[mi] = *(const bf16x8*)(As + (size_t)r*64 + cs*8);
      }
      #pragma unroll
      for (int ni = 0; ni < 2; ++ni){
        int r  = wc*32 + ni*16 + (lane & 15);
        int c  = kk*4 + (lane >> 4);
        int cs = c ^ (r & 7);
        wf[ni] = *(const bf16x8*)(Wt + (size_t)r*64 + cs*8);
      }
      #pragma unroll
      for (int mi = 0; mi < 2; ++mi)
        #pragma unroll
        for (int ni = 0; ni < 2; ++ni)
          acc[mi][ni] = mfma16(af[mi], wf[ni], acc[mi][ni]);
    }
    __syncthreads();
  }

  #pragma unroll
  for (int mi = 0; mi < 2; ++mi){
    #pragma unroll
    for (int ni = 0; ni < 2; ++ni){
      int rbase = m0 + wr*32 + mi*16 + (lane >> 4)*4;
      int col   = n0 + wc*32 + ni*16 + (lane & 15);
      if (col < Nreal){
        float bb = 0.f;
        if (bias0) bb += bias0[col];
        if (bias1) bb += bias1[col];
        #pragma unroll
        for (int r4 = 0; r4 < 4; ++r4)
          Cf[(size_t)(rbase + r4)*ldc + col] = acc[mi][ni][r4] + bb;
      }
    }
  }
}

// grid-mapped 64-tile GEMM (used for gi)
__global__ __launch_bounds__(256) void gemm_bt(
    const float* __restrict__ A, const float* __restrict__ W,
    const float* __restrict__ bias0, const float* __restrict__ bias1,
    float* __restrict__ Cf, int K, int Nreal, int ldc)
{
  __shared__ __bf16 As[64*64];
  __shared__ __bf16 Wt[64*64];
  gemm64_core(A, W, bias0, bias1, Cf, K, Nreal, ldc,
              blockIdx.y*64, blockIdx.x*64, As, Wt);
}

// fused: blocks 0..31 -> sProjP = s@se_w^T + se_b + xe_b (N=512)
//        blocks 32..127 -> gh = s@w_hh^T + b_hh (N=1536)
__global__ __launch_bounds__(256) void gemm_small_fused(
    const float* __restrict__ s,
    const float* __restrict__ se_w, const float* __restrict__ se_b,
    const float* __restrict__ xe_b, float* __restrict__ sProjP,
    const float* __restrict__ w_hh, const float* __restrict__ b_hh,
    float* __restrict__ gh)
{
  __shared__ __bf16 As[64*64];
  __shared__ __bf16 Wt[64*64];
  int bid = blockIdx.x;
  if (bid < 32){
    gemm64_core(s, se_w, se_b, xe_b, sProjP, 512, 512, 512,
                (bid >> 3)*64, (bid & 7)*64, As, Wt);
  } else {
    int b2 = bid - 32;
    gemm64_core(s, w_hh, b_hh, nullptr, gh, 512, 1536, 1536,
                (b2 / 24)*64, (b2 % 24)*64, As, Wt);
  }
}

// ---------------------------------------------------------------------------
// 128x128-tile GEMM (f32 in, f32 out), for logits. 4 waves, each 64x64.
__global__ __launch_bounds__(256) void gemm128_bt(
    const float* __restrict__ A, const float* __restrict__ W,
    const float* __restrict__ bias, float* __restrict__ C,
    int K, int Nreal, int ldc)
{
  const int tid  = threadIdx.x;
  const int lane = tid & 63;
  const int wid  = tid >> 6;
  const int wr = wid >> 1, wc = wid & 1;
  const int n0 = blockIdx.x * 128;
  const int m0 = blockIdx.y * 128;

  __shared__ __bf16 As[128*64];
  __shared__ __bf16 Bs[128*64];

  f32x4 acc[4][4] = {};
  const int nkt = K >> 6;
  for (int kt = 0; kt < nkt; ++kt){
    #pragma unroll
    for (int i = 0; i < 4; ++i){
      int s  = i*256 + tid;
      int r  = s >> 3;
      int cp = s & 7;
      int cg = cp ^ (r & 7);
      {
        const float* g = A + (size_t)(m0 + r)*K + kt*64 + cg*8;
        f32x4 v0 = *(const f32x4*)g;
        f32x4 v1 = *(const f32x4*)(g + 4);
        *(bf16x8*)(As + (size_t)s*8) = cvt8(v0, v1);
      }
      {
        int rw = n0 + r;
        if (rw >= Nreal) rw = Nreal - 1;
        const float* g = W + (size_t)rw*K + kt*64 + cg*8;
        f32x4 v0 = *(const f32x4*)g;
        f32x4 v1 = *(const f32x4*)(g + 4);
        *(bf16x8*)(Bs + (size_t)s*8) = cvt8(v0, v1);
      }
    }
    __syncthreads();
    #pragma unroll
    for (int kk = 0; kk < 2; ++kk){
      bf16x8 af[4], bfr[4];
      #pragma unroll
      for (int mi = 0; mi < 4; ++mi){
        int r  = wr*64 + mi*16 + (lane & 15);
        int c  = kk*4 + (lane >> 4);
        int cs = c ^ (r & 7);
        af[mi] = *(const bf16x8*)(As + (size_t)r*64 + cs*8);
      }
      #pragma unroll
      for (int ni = 0; ni < 4; ++ni){
        int r  = wc*64 + ni*16 + (lane & 15);
        int c  = kk*4 + (lane >> 4);
        int cs = c ^ (r & 7);
        bfr[ni] = *(const bf16x8*)(Bs + (size_t)r*64 + cs*8);
      }
      #pragma unroll
      for (int mi = 0; mi < 4; ++mi)
        #pragma unroll
        for (int ni = 0; ni < 4; ++ni)
          acc[mi][ni] = mfma16(af[mi], bfr[ni], acc[mi][ni]);
    }
    __syncthreads();
  }

  #pragma unroll
  for (int mi = 0; mi < 4; ++mi){
    #pragma unroll
    for (int ni = 0; ni < 4; ++ni){
      int rbase = m0 + wr*64 + mi*16 + (lane >> 4)*4;
      int col   = n0 + wc*64 + ni*16 + (lane & 15);
      if (col < Nreal){
        float bb = bias ? bias[col] : 0.f;
        #pragma unroll
        for (int r4 = 0; r4 < 4; ++r4)
          C[(size_t)(rbase + r4)*ldc + col] = acc[mi][ni][r4] + bb;
      }
    }
  }
}

// ---------------------------------------------------------------------------
// attention scores v2: 128x128x(K=512) GEMM block + fused tanh-reduce epilogue.
// grid = (4 n-blocks, 512 m-blocks). B from pre-swizzled wswz (straight copy).
// Writes partial score to scores4[row][nb]; softmax sums the 4 partials.
__global__ __launch_bounds__(256) void attn_scores2(
    const float* __restrict__ x, const __bf16* __restrict__ wswz,
    const float* __restrict__ sProjPlus, const float* __restrict__ we_w,
    float* __restrict__ scores4)
{
  const int tid  = threadIdx.x;
  const int lane = tid & 63;
  const int wid  = tid >> 6;
  const int wr = wid >> 1, wc = wid & 1;
  const int nb = blockIdx.x;          // 0..3 (a-dim 128-col block)
  const int m0 = blockIdx.y * 128;    // global row = b*256 + t
  const int b  = m0 >> 8;

  __shared__ __bf16 As[128*64];
  __shared__ __bf16 Bs[128*64];
  __shared__ float  sc[2][128];

  f32x4 acc[4][4] = {};
  #pragma unroll 1
  for (int kt = 0; kt < 8; ++kt){
    #pragma unroll
    for (int i = 0; i < 4; ++i){
      int s  = i*256 + tid;
      int r  = s >> 3;
      int cp = s & 7;
      int cg = cp ^ (r & 7);
      const float* g = x + (size_t)(m0 + r)*512 + kt*64 + cg*8;
      f32x4 v0 = *(const f32x4*)g;
      f32x4 v1 = *(const f32x4*)(g + 4);
      *(bf16x8*)(As + (size_t)s*8) = cvt8(v0, v1);
    }
    {
      const bf16x8* t0 = (const bf16x8*)(wswz + (size_t)((2*nb)*8   + kt)*4096);
      const bf16x8* t1 = (const bf16x8*)(wswz + (size_t)((2*nb+1)*8 + kt)*4096);
      bf16x8* bs = (bf16x8*)Bs;
      bs[tid]       = t0[tid];
      bs[tid + 256] = t0[tid + 256];
      bs[tid + 512] = t1[tid];
      bs[tid + 768] = t1[tid + 256];
    }
    __syncthreads();
    #pragma unroll
    for (int kk = 0; kk < 2; ++kk){
      bf16x8 af[4], bfr[4];
      #pragma unroll
      for (int mi = 0; mi < 4; ++mi){
        int r  = wr*64 + mi*16 + (lane & 15);
        int c  = kk*4 + (lane >> 4);
        int cs = c ^ (r & 7);
        af[mi] = *(const bf16x8*)(As + (size_t)r*64 + cs*8);
      }
      #pragma unroll
      for (int ni = 0; ni < 4; ++ni){
        int r  = wc*64 + ni*16 + (lane & 15);
        int c  = kk*4 + (lane >> 4);
        int cs = c ^ (r & 7);
        bfr[ni] = *(const bf16x8*)(Bs + (size_t)r*64 + cs*8);
      }
      #pragma unroll
      for (int mi = 0; mi < 4; ++mi)
        #pragma unroll
        for (int ni = 0; ni < 4; ++ni)
          acc[mi][ni] = mfma16(af[mi], bfr[ni], acc[mi][ni]);
    }
    __syncthreads();
  }

  // fused epilogue: tanh(xProj + sProj) * we_w, reduce over the 128 cols
  float part[4][4] = {};
  #pragma unroll
  for (int ni = 0; ni < 4; ++ni){
    int col  = nb*128 + wc*64 + ni*16 + (lane & 15);
    float sp = sProjPlus[b*512 + col];
    float wv = we_w[col];
    #pragma unroll
    for (int mi = 0; mi < 4; ++mi)
      #pragma unroll
      for (int r4 = 0; r4 < 4; ++r4)
        part[mi][r4] += fast_tanh(acc[mi][ni][r4] + sp) * wv;
  }
  #pragma unroll
  for (int mi = 0; mi < 4; ++mi)
    #pragma unroll
    for (int r4 = 0; r4 < 4; ++r4){
      float v = part[mi][r4];
      v += __shfl_xor(v, 1);
      v += __shfl_xor(v, 2);
      v += __shfl_xor(v, 4);
      v += __shfl_xor(v, 8);
      if ((lane & 15) == 0)
        sc[wc][wr*64 + mi*16 + (lane >> 4)*4 + r4] = v;
    }
  __syncthreads();
  if (tid < 128)
    scores4[(size_t)(m0 + tid)*4 + nb] = sc[0][tid] + sc[1][tid];
}

// ---------------------------------------------------------------------------
__global__ __launch_bounds__(256) void softmax_k(const float* __restrict__ scores4,
                                                 float* __restrict__ alpha){
  int b = blockIdx.x, t = threadIdx.x;
  __shared__ float red[256];
  f32x4 s4 = *(const f32x4*)(scores4 + (size_t)(b*256 + t)*4);
  float v = (s4[0] + s4[1]) + (s4[2] + s4[3]);
  red[t] = v; __syncthreads();
  for (int o = 128; o > 0; o >>= 1){
    if (t < o) red[t] = fmaxf(red[t], red[t+o]);
    __syncthreads();
  }
  float m = red[0]; __syncthreads();
  float e = __expf(v - m);
  red[t] = e; __syncthreads();
  for (int o = 128; o > 0; o >>= 1){
    if (t < o) red[t] += red[t+o];
    __syncthreads();
  }
  alpha[b*256 + t] = e / red[0];
}

// ---------------------------------------------------------------------------
// context[b,:] = sum_t alpha[b,t]*x[b,t,:]; cc = [yProj | context].
// 512 threads: 2-way split over t, LDS combine.
__global__ __launch_bounds__(512) void context_cc(
    const float* __restrict__ x, const float* __restrict__ alpha,
    const float* __restrict__ emb, const int* __restrict__ yPrev,
    float* __restrict__ cc)
{
  int b = blockIdx.x, th = threadIdx.x;
  __shared__ float al[256];
  __shared__ float px[512], py[512];
  if (th < 256) al[th] = alpha[b*256 + th];
  __syncthreads();
  int cp = th & 255, half = th >> 8;
  f32x2 acc = {0.f, 0.f};
  const f32x2* xb = (const f32x2*)(x + (size_t)b*131072) + cp;
  #pragma unroll 4
  for (int i = half*128; i < half*128 + 128; ++i){
    f32x2 v = xb[(size_t)i*256];
    acc.x += al[i]*v.x;
    acc.y += al[i]*v.y;
  }
  px[th] = acc.x; py[th] = acc.y;
  __syncthreads();
  if (th < 256){
    f32x2 e2 = ((const f32x2*)(emb + (size_t)yPrev[b]*512))[th];
    f32x2* ccb = (f32x2*)(cc + (size_t)b*1024);
    ccb[th] = e2;
    f32x2 c2 = { px[th] + px[th+256], py[th] + py[th+256] };
    ccb[256 + th] = c2;
  }
}

// ---------------------------------------------------------------------------
__global__ __launch_bounds__(256) void gates_k(
    const float* __restrict__ gi, const float* __restrict__ gh,
    const float* __restrict__ s, float* __restrict__ h_out)
{
  int idx = blockIdx.x*256 + threadIdx.x;   // 0..131071
  int b = idx >> 9, j = idx & 511;
  const float* gib = gi + (size_t)b*1536;
  const float* ghb = gh + (size_t)b*1536;
  float r  = sigm(gib[j]        + ghb[j]);
  float z  = sigm(gib[512 + j]  + ghb[512 + j]);
  float nv = fast_tanh(gib[1024 + j] + r*ghb[1024 + j]);
  float sv = s[idx];
  float h  = (1.f - z)*nv + z*sv;
  h_out[idx] = h;
}

// ---------------------------------------------------------------------------
extern "C" void kernel_launch(void* const* d_in, const int* in_sizes, int n_in,
                              void* d_out, int out_size, void* d_ws, size_t ws_size,
                              hipStream_t stream)
{
  const float* x     = (const float*)d_in[0];
  const float* sPrev = (const float*)d_in[1];   // (1,B,SD) -> [256,512]
  const int*   yPrev = (const int*)d_in[2];
  const float* xe_w  = (const float*)d_in[3];
  const float* xe_b  = (const float*)d_in[4];
  const float* se_w  = (const float*)d_in[5];
  const float* se_b  = (const float*)d_in[6];
  const float* we_w  = (const float*)d_in[7];
  // d_in[8] = we_b: constant shift, cancels in softmax -> unused
  const float* emb   = (const float*)d_in[9];
  const float* w_ih  = (const float*)d_in[10];
  const float* w_hh  = (const float*)d_in[11];
  const float* b_ih  = (const float*)d_in[12];
  const float* b_hh  = (const float*)d_in[13];
  const float* fc_w  = (const float*)d_in[14];
  const float* fc_b  = (const float*)d_in[15];

  char* ws = (char*)d_ws;
  __bf16* wswz   = (__bf16*)(ws);               // 512 KB  (xe_w bf16 swizzled)
  float* sProjP  = (float*)(ws + 524288);       // 512 KB  [256,512]
  float* gh      = (float*)(ws + 1048576);      // 1.5 MB  [256,1536]
  float* scores4 = (float*)(ws + 2621440);      // 1 MB    [65536,4]
  float* alpha   = (float*)(ws + 3670016);      // 256 KB
  float* cc      = (float*)(ws + 2621440);      // aliases scores4 (dead after softmax)
  float* gi      = (float*)(ws + 3932160);      // 1.5 MB  [256,1536]
  // high-water: 5.25 MB

  // f32 outputs, concatenated: logits [256,6625], h [256,512]
  float* logits_out = (float*)d_out;
  float* h_out      = logits_out + (size_t)256*6625;

  cvt_xew<<<128, 256, 0, stream>>>(xe_w, wswz);
  gemm_small_fused<<<128, 256, 0, stream>>>(sPrev, se_w, se_b, xe_b, sProjP,
                                            w_hh, b_hh, gh);
  attn_scores2<<<dim3(4, 512), 256, 0, stream>>>(x, wswz, sProjP, we_w, scores4);
  softmax_k<<<256, 256, 0, stream>>>(scores4, alpha);
  context_cc<<<256, 512, 0, stream>>>(x, alpha, emb, yPrev, cc);
  // gi = cc @ w_ih^T + b_ih
  gemm_bt<<<dim3(24,4), 256, 0, stream>>>(cc, w_ih, b_ih, nullptr, gi, 1024, 1536, 1536);
  gates_k<<<512, 256, 0, stream>>>(gi, gh, sPrev, h_out);
  // logits = h @ fc_w^T + fc_b (reads h from d_out; N=6625 tail-guarded)
  gemm128_bt<<<dim3(52,2), 256, 0, stream>>>(h_out, fc_w, fc_b, logits_out, 512, 6625, 6625);
}

// Round 5
// 384.238 us; speedup vs baseline: 1.1661x; 1.0217x over previous
//
#include <hip/hip_runtime.h>
#include <stdint.h>
#include <stddef.h>

typedef __attribute__((ext_vector_type(4))) float f32x4;
typedef __attribute__((ext_vector_type(2))) float f32x2;
typedef __attribute__((ext_vector_type(8))) __bf16 bf16x8;

#define DEVI static __device__ __forceinline__

DEVI f32x4 mfma16(bf16x8 a, bf16x8 b, f32x4 c){
  return __builtin_amdgcn_mfma_f32_16x16x32_bf16(a, b, c, 0, 0, 0);
}

DEVI bf16x8 cvt8(f32x4 a, f32x4 b){
  bf16x8 o;
  o[0]=(__bf16)a[0]; o[1]=(__bf16)a[1]; o[2]=(__bf16)a[2]; o[3]=(__bf16)a[3];
  o[4]=(__bf16)b[0]; o[5]=(__bf16)b[1]; o[6]=(__bf16)b[2]; o[7]=(__bf16)b[3];
  return o;
}

DEVI float fast_tanh(float x){ return 1.f - 2.f/(__expf(2.f*x)+1.f); }
DEVI float sigm(float x){ return 1.f/(1.f+__expf(-x)); }

// ---------------------------------------------------------------------------
// xe_w f32 [512 a][512 x] -> bf16, tiled (nt,kt) 64x64, slot-linear with
// chunk-XOR swizzle. slot s in tile: r=s>>3, cp=s&7, holds k-chunk cg=cp^(r&7).
__global__ __launch_bounds__(256) void cvt_xew(const float* __restrict__ xe_w,
                                               __bf16* __restrict__ wswz){
  int g = blockIdx.x*256 + threadIdx.x;   // 0..32767
  int tile = g >> 9;                      // nt*8 + kt
  int s = g & 511;
  int nt = tile >> 3, kt = tile & 7;
  int r = s >> 3, cp = s & 7;
  int cg = cp ^ (r & 7);
  const float* src = xe_w + (size_t)(nt*64 + r)*512 + kt*64 + cg*8;
  f32x4 a = *(const f32x4*)src;
  f32x4 b = *(const f32x4*)(src + 4);
  *(bf16x8*)(wswz + (size_t)g*8) = cvt8(a, b);
}

// ---------------------------------------------------------------------------
// 64x64-tile GEMM core (C = A*W^T + b0 + b1), bf16 MFMA, XOR-swizzled LDS.
DEVI void gemm64_core(const float* __restrict__ A, const float* __restrict__ W,
                      const float* __restrict__ bias0, const float* __restrict__ bias1,
                      float* __restrict__ Cf, int K, int Nreal, int ldc,
                      int m0, int n0, __bf16* As, __bf16* Wt)
{
  const int tid  = threadIdx.x;
  const int lane = tid & 63;
  const int wid  = tid >> 6;
  const int wr = wid >> 1, wc = wid & 1;

  f32x4 acc[2][2] = {};
  const int nkt = K >> 6;
  for (int kt = 0; kt < nkt; ++kt){
    #pragma unroll
    for (int ss = 0; ss < 2; ++ss){
      int s  = ss*256 + tid;
      int r  = s >> 3;
      int cp = s & 7;
      int cg = cp ^ (r & 7);
      {
        const float* g = A + (size_t)(m0 + r)*K + kt*64 + cg*8;
        f32x4 v0 = *(const f32x4*)g;
        f32x4 v1 = *(const f32x4*)(g + 4);
        *(bf16x8*)(As + (size_t)s*8) = cvt8(v0, v1);
      }
      {
        int rw = n0 + r;
        if (rw >= Nreal) rw = Nreal - 1;
        const float* g = W + (size_t)rw*K + kt*64 + cg*8;
        f32x4 v0 = *(const f32x4*)g;
        f32x4 v1 = *(const f32x4*)(g + 4);
        *(bf16x8*)(Wt + (size_t)s*8) = cvt8(v0, v1);
      }
    }
    __syncthreads();
    #pragma unroll
    for (int kk = 0; kk < 2; ++kk){
      bf16x8 af[2], wf[2];
      #pragma unroll
      for (int mi = 0; mi < 2; ++mi){
        int r  = wr*32 + mi*16 + (lane & 15);
        int c  = kk*4 + (lane >> 4);
        int cs = c ^ (r & 7);
        af[mi] = *(const bf16x8*)(As + (size_t)r*64 + cs*8);
      }
      #pragma unroll
      for (int ni = 0; ni < 2; ++ni){
        int r  = wc*32 + ni*16 + (lane & 15);
        int c  = kk*4 + (lane >> 4);
        int cs = c ^ (r & 7);
        wf[ni] = *(const bf16x8*)(Wt + (size_t)r*64 + cs*8);
      }
      #pragma unroll
      for (int mi = 0; mi < 2; ++mi)
        #pragma unroll
        for (int ni = 0; ni < 2; ++ni)
          acc[mi][ni] = mfma16(af[mi], wf[ni], acc[mi][ni]);
    }
    __syncthreads();
  }

  #pragma unroll
  for (int mi = 0; mi < 2; ++mi){
    #pragma unroll
    for (int ni = 0; ni < 2; ++ni){
      int rbase = m0 + wr*32 + mi*16 + (lane >> 4)*4;
      int col   = n0 + wc*32 + ni*16 + (lane & 15);
      if (col < Nreal){
        float bb = 0.f;
        if (bias0) bb += bias0[col];
        if (bias1) bb += bias1[col];
        #pragma unroll
        for (int r4 = 0; r4 < 4; ++r4)
          Cf[(size_t)(rbase + r4)*ldc + col] = acc[mi][ni][r4] + bb;
      }
    }
  }
}

// grid-mapped 64-tile GEMM (used for gi)
__global__ __launch_bounds__(256) void gemm_bt(
    const float* __restrict__ A, const float* __restrict__ W,
    const float* __restrict__ bias0, const float* __restrict__ bias1,
    float* __restrict__ Cf, int K, int Nreal, int ldc)
{
  __shared__ __bf16 As[64*64];
  __shared__ __bf16 Wt[64*64];
  gemm64_core(A, W, bias0, bias1, Cf, K, Nreal, ldc,
              blockIdx.y*64, blockIdx.x*64, As, Wt);
}

// fused: blocks 0..31 -> sProjP = s@se_w^T + se_b + xe_b (N=512)
//        blocks 32..127 -> gh = s@w_hh^T + b_hh (N=1536)
__global__ __launch_bounds__(256) void gemm_small_fused(
    const float* __restrict__ s,
    const float* __restrict__ se_w, const float* __restrict__ se_b,
    const float* __restrict__ xe_b, float* __restrict__ sProjP,
    const float* __restrict__ w_hh, const float* __restrict__ b_hh,
    float* __restrict__ gh)
{
  __shared__ __bf16 As[64*64];
  __shared__ __bf16 Wt[64*64];
  int bid = blockIdx.x;
  if (bid < 32){
    gemm64_core(s, se_w, se_b, xe_b, sProjP, 512, 512, 512,
                (bid >> 3)*64, (bid & 7)*64, As, Wt);
  } else {
    int b2 = bid - 32;
    gemm64_core(s, w_hh, b_hh, nullptr, gh, 512, 1536, 1536,
                (b2 / 24)*64, (b2 % 24)*64, As, Wt);
  }
}

// ---------------------------------------------------------------------------
// 128x128-tile GEMM (f32 in, f32 out), for logits. 4 waves, each 64x64.
__global__ __launch_bounds__(256) void gemm128_bt(
    const float* __restrict__ A, const float* __restrict__ W,
    const float* __restrict__ bias, float* __restrict__ C,
    int K, int Nreal, int ldc)
{
  const int tid  = threadIdx.x;
  const int lane = tid & 63;
  const int wid  = tid >> 6;
  const int wr = wid >> 1, wc = wid & 1;
  const int n0 = blockIdx.x * 128;
  const int m0 = blockIdx.y * 128;

  __shared__ __bf16 As[128*64];
  __shared__ __bf16 Bs[128*64];

  f32x4 acc[4][4] = {};
  const int nkt = K >> 6;
  for (int kt = 0; kt < nkt; ++kt){
    #pragma unroll
    for (int i = 0; i < 4; ++i){
      int s  = i*256 + tid;
      int r  = s >> 3;
      int cp = s & 7;
      int cg = cp ^ (r & 7);
      {
        const float* g = A + (size_t)(m0 + r)*K + kt*64 + cg*8;
        f32x4 v0 = *(const f32x4*)g;
        f32x4 v1 = *(const f32x4*)(g + 4);
        *(bf16x8*)(As + (size_t)s*8) = cvt8(v0, v1);
      }
      {
        int rw = n0 + r;
        if (rw >= Nreal) rw = Nreal - 1;
        const float* g = W + (size_t)rw*K + kt*64 + cg*8;
        f32x4 v0 = *(const f32x4*)g;
        f32x4 v1 = *(const f32x4*)(g + 4);
        *(bf16x8*)(Bs + (size_t)s*8) = cvt8(v0, v1);
      }
    }
    __syncthreads();
    #pragma unroll
    for (int kk = 0; kk < 2; ++kk){
      bf16x8 af[4], bfr[4];
      #pragma unroll
      for (int mi = 0; mi < 4; ++mi){
        int r  = wr*64 + mi*16 + (lane & 15);
        int c  = kk*4 + (lane >> 4);
        int cs = c ^ (r & 7);
        af[mi] = *(const bf16x8*)(As + (size_t)r*64 + cs*8);
      }
      #pragma unroll
      for (int ni = 0; ni < 4; ++ni){
        int r  = wc*64 + ni*16 + (lane & 15);
        int c  = kk*4 + (lane >> 4);
        int cs = c ^ (r & 7);
        bfr[ni] = *(const bf16x8*)(Bs + (size_t)r*64 + cs*8);
      }
      #pragma unroll
      for (int mi = 0; mi < 4; ++mi)
        #pragma unroll
        for (int ni = 0; ni < 4; ++ni)
          acc[mi][ni] = mfma16(af[mi], bfr[ni], acc[mi][ni]);
    }
    __syncthreads();
  }

  #pragma unroll
  for (int mi = 0; mi < 4; ++mi){
    #pragma unroll
    for (int ni = 0; ni < 4; ++ni){
      int rbase = m0 + wr*64 + mi*16 + (lane >> 4)*4;
      int col   = n0 + wc*64 + ni*16 + (lane & 15);
      if (col < Nreal){
        float bb = bias ? bias[col] : 0.f;
        #pragma unroll
        for (int r4 = 0; r4 < 4; ++r4)
          C[(size_t)(rbase + r4)*ldc + col] = acc[mi][ni][r4] + bb;
      }
    }
  }
}

// ---------------------------------------------------------------------------
// attention scores v3: 128x128x(K=512) GEMM + fused tanh-reduce epilogue.
// 1D grid 2048, XCD-aware mapping: the 4 nb-blocks sharing an x m-panel get
// adjacent slots on the SAME XCD -> panel fetched once into that XCD's L2.
__global__ __launch_bounds__(256) void attn_scores2(
    const float* __restrict__ x, const __bf16* __restrict__ wswz,
    const float* __restrict__ sProjPlus, const float* __restrict__ we_w,
    float* __restrict__ scores4)
{
  const int tid  = threadIdx.x;
  const int lane = tid & 63;
  const int wid  = tid >> 6;
  const int wr = wid >> 1, wc = wid & 1;

  const int bid  = blockIdx.x;        // 0..2047, HW: XCD = bid & 7
  const int xcd  = bid & 7;
  const int slot = bid >> 3;          // 0..255 within XCD
  const int mb   = xcd*64 + (slot >> 2);
  const int nb   = slot & 3;          // a-dim 128-col block
  const int m0   = mb * 128;          // global row = b*256 + t
  const int b    = m0 >> 8;

  __shared__ __bf16 As[128*64];
  __shared__ __bf16 Bs[128*64];
  __shared__ float  sc[2][128];

  f32x4 acc[4][4] = {};
  #pragma unroll 1
  for (int kt = 0; kt < 8; ++kt){
    #pragma unroll
    for (int i = 0; i < 4; ++i){
      int s  = i*256 + tid;
      int r  = s >> 3;
      int cp = s & 7;
      int cg = cp ^ (r & 7);
      const float* g = x + (size_t)(m0 + r)*512 + kt*64 + cg*8;
      f32x4 v0 = *(const f32x4*)g;
      f32x4 v1 = *(const f32x4*)(g + 4);
      *(bf16x8*)(As + (size_t)s*8) = cvt8(v0, v1);
    }
    {
      const bf16x8* t0 = (const bf16x8*)(wswz + (size_t)((2*nb)*8   + kt)*4096);
      const bf16x8* t1 = (const bf16x8*)(wswz + (size_t)((2*nb+1)*8 + kt)*4096);
      bf16x8* bs = (bf16x8*)Bs;
      bs[tid]       = t0[tid];
      bs[tid + 256] = t0[tid + 256];
      bs[tid + 512] = t1[tid];
      bs[tid + 768] = t1[tid + 256];
    }
    __syncthreads();
    #pragma unroll
    for (int kk = 0; kk < 2; ++kk){
      bf16x8 af[4], bfr[4];
      #pragma unroll
      for (int mi = 0; mi < 4; ++mi){
        int r  = wr*64 + mi*16 + (lane & 15);
        int c  = kk*4 + (lane >> 4);
        int cs = c ^ (r & 7);
        af[mi] = *(const bf16x8*)(As + (size_t)r*64 + cs*8);
      }
      #pragma unroll
      for (int ni = 0; ni < 4; ++ni){
        int r  = wc*64 + ni*16 + (lane & 15);
        int c  = kk*4 + (lane >> 4);
        int cs = c ^ (r & 7);
        bfr[ni] = *(const bf16x8*)(Bs + (size_t)r*64 + cs*8);
      }
      #pragma unroll
      for (int mi = 0; mi < 4; ++mi)
        #pragma unroll
        for (int ni = 0; ni < 4; ++ni)
          acc[mi][ni] = mfma16(af[mi], bfr[ni], acc[mi][ni]);
    }
    __syncthreads();
  }

  // fused epilogue: tanh(xProj + sProj) * we_w, reduce over the 128 cols
  float part[4][4] = {};
  #pragma unroll
  for (int ni = 0; ni < 4; ++ni){
    int col  = nb*128 + wc*64 + ni*16 + (lane & 15);
    float sp = sProjPlus[b*512 + col];
    float wv = we_w[col];
    #pragma unroll
    for (int mi = 0; mi < 4; ++mi)
      #pragma unroll
      for (int r4 = 0; r4 < 4; ++r4)
        part[mi][r4] += fast_tanh(acc[mi][ni][r4] + sp) * wv;
  }
  #pragma unroll
  for (int mi = 0; mi < 4; ++mi)
    #pragma unroll
    for (int r4 = 0; r4 < 4; ++r4){
      float v = part[mi][r4];
      v += __shfl_xor(v, 1);
      v += __shfl_xor(v, 2);
      v += __shfl_xor(v, 4);
      v += __shfl_xor(v, 8);
      if ((lane & 15) == 0)
        sc[wc][wr*64 + mi*16 + (lane >> 4)*4 + r4] = v;
    }
  __syncthreads();
  if (tid < 128)
    scores4[(size_t)(m0 + tid)*4 + nb] = sc[0][tid] + sc[1][tid];
}

// ---------------------------------------------------------------------------
__global__ __launch_bounds__(256) void softmax_k(const float* __restrict__ scores4,
                                                 float* __restrict__ alpha){
  int b = blockIdx.x, t = threadIdx.x;
  __shared__ float red[256];
  f32x4 s4 = *(const f32x4*)(scores4 + (size_t)(b*256 + t)*4);
  float v = (s4[0] + s4[1]) + (s4[2] + s4[3]);
  red[t] = v; __syncthreads();
  for (int o = 128; o > 0; o >>= 1){
    if (t < o) red[t] = fmaxf(red[t], red[t+o]);
    __syncthreads();
  }
  float m = red[0]; __syncthreads();
  float e = __expf(v - m);
  red[t] = e; __syncthreads();
  for (int o = 128; o > 0; o >>= 1){
    if (t < o) red[t] += red[t+o];
    __syncthreads();
  }
  alpha[b*256 + t] = e / red[0];
}

// ---------------------------------------------------------------------------
// context[b,:] = sum_t alpha[b,t]*x[b,t,:]; cc = [yProj | context].
// 1024 threads: 8 groups of 128, each group 32 rows, f32x4 loads (1KB/wave),
// LDS combine. One block per b.
__global__ __launch_bounds__(1024) void context_cc(
    const float* __restrict__ x, const float* __restrict__ alpha,
    const float* __restrict__ emb, const int* __restrict__ yPrev,
    float* __restrict__ cc)
{
  int b = blockIdx.x, th = threadIdx.x;
  int g = th >> 7, cp = th & 127;     // group 0..7, f32x4-col 0..127
  __shared__ float al[256];
  __shared__ f32x4 psum[8][128];      // 16 KB
  if (th < 256) al[th] = alpha[b*256 + th];
  __syncthreads();
  const f32x4* xb = (const f32x4*)(x + (size_t)b*131072);
  f32x4 acc = {0.f, 0.f, 0.f, 0.f};
  const int r0 = g*32;
  #pragma unroll 4
  for (int i = 0; i < 32; ++i){
    f32x4 v = xb[(size_t)(r0 + i)*128 + cp];
    float a = al[r0 + i];
    acc[0] += a*v[0]; acc[1] += a*v[1]; acc[2] += a*v[2]; acc[3] += a*v[3];
  }
  psum[g][cp] = acc;
  __syncthreads();
  f32x4* ccb = (f32x4*)(cc + (size_t)b*1024);
  if (th < 128){
    f32x4 s = psum[0][th];
    #pragma unroll
    for (int gg = 1; gg < 8; ++gg){
      f32x4 p = psum[gg][th];
      s[0] += p[0]; s[1] += p[1]; s[2] += p[2]; s[3] += p[3];
    }
    ccb[128 + th] = s;                // context -> cols [512,1024)
  } else if (th < 256){
    int j = th - 128;
    ccb[j] = ((const f32x4*)(emb + (size_t)yPrev[b]*512))[j];  // yProj
  }
}

// ---------------------------------------------------------------------------
__global__ __launch_bounds__(256) void gates_k(
    const float* __restrict__ gi, const float* __restrict__ gh,
    const float* __restrict__ s, float* __restrict__ h_out)
{
  int idx = blockIdx.x*256 + threadIdx.x;   // 0..131071
  int b = idx >> 9, j = idx & 511;
  const float* gib = gi + (size_t)b*1536;
  const float* ghb = gh + (size_t)b*1536;
  float r  = sigm(gib[j]        + ghb[j]);
  float z  = sigm(gib[512 + j]  + ghb[512 + j]);
  float nv = fast_tanh(gib[1024 + j] + r*ghb[1024 + j]);
  float sv = s[idx];
  float h  = (1.f - z)*nv + z*sv;
  h_out[idx] = h;
}

// ---------------------------------------------------------------------------
extern "C" void kernel_launch(void* const* d_in, const int* in_sizes, int n_in,
                              void* d_out, int out_size, void* d_ws, size_t ws_size,
                              hipStream_t stream)
{
  const float* x     = (const float*)d_in[0];
  const float* sPrev = (const float*)d_in[1];   // (1,B,SD) -> [256,512]
  const int*   yPrev = (const int*)d_in[2];
  const float* xe_w  = (const float*)d_in[3];
  const float* xe_b  = (const float*)d_in[4];
  const float* se_w  = (const float*)d_in[5];
  const float* se_b  = (const float*)d_in[6];
  const float* we_w  = (const float*)d_in[7];
  // d_in[8] = we_b: constant shift, cancels in softmax -> unused
  const float* emb   = (const float*)d_in[9];
  const float* w_ih  = (const float*)d_in[10];
  const float* w_hh  = (const float*)d_in[11];
  const float* b_ih  = (const float*)d_in[12];
  const float* b_hh  = (const float*)d_in[13];
  const float* fc_w  = (const float*)d_in[14];
  const float* fc_b  = (const float*)d_in[15];

  char* ws = (char*)d_ws;
  __bf16* wswz   = (__bf16*)(ws);               // 512 KB  (xe_w bf16 swizzled)
  float* sProjP  = (float*)(ws + 524288);       // 512 KB  [256,512]
  float* gh      = (float*)(ws + 1048576);      // 1.5 MB  [256,1536]
  float* scores4 = (float*)(ws + 2621440);      // 1 MB    [65536,4]
  float* alpha   = (float*)(ws + 3670016);      // 256 KB
  float* cc      = (float*)(ws + 2621440);      // aliases scores4 (dead after softmax)
  float* gi      = (float*)(ws + 3932160);      // 1.5 MB  [256,1536]
  // high-water: 5.25 MB

  // f32 outputs, concatenated: logits [256,6625], h [256,512]
  float* logits_out = (float*)d_out;
  float* h_out      = logits_out + (size_t)256*6625;

  cvt_xew<<<128, 256, 0, stream>>>(xe_w, wswz);
  gemm_small_fused<<<128, 256, 0, stream>>>(sPrev, se_w, se_b, xe_b, sProjP,
                                            w_hh, b_hh, gh);
  attn_scores2<<<2048, 256, 0, stream>>>(x, wswz, sProjP, we_w, scores4);
  softmax_k<<<256, 256, 0, stream>>>(scores4, alpha);
  context_cc<<<256, 1024, 0, stream>>>(x, alpha, emb, yPrev, cc);
  // gi = cc @ w_ih^T + b_ih
  gemm_bt<<<dim3(24,4), 256, 0, stream>>>(cc, w_ih, b_ih, nullptr, gi, 1024, 1536, 1536);
  gates_k<<<512, 256, 0, stream>>>(gi, gh, sPrev, h_out);
  // logits = h @ fc_w^T + fc_b (reads h from d_out; N=6625 tail-guarded)
  gemm128_bt<<<dim3(52,2), 256, 0, stream>>>(h_out, fc_w, fc_b, logits_out, 512, 6625, 6625);
}